// Round 11
// baseline (202.431 us; speedup 1.0000x reference)
//
#include <hip/hip_runtime.h>
#include <hip/hip_bf16.h>

#define NNODES 100000
#define NEDGES 1600000
#define IN_C   256
#define OUT_C  128
#define NSLAB  4          // 4 slabs x 32 channels; slab pinned to XCD pair

typedef short bf16x8 __attribute__((ext_vector_type(8)));
typedef float f32x4  __attribute__((ext_vector_type(4)));

static __device__ __forceinline__ unsigned short f2bf(float f) {
    union { float f; unsigned u; } c; c.f = f;
    unsigned r = c.u + 0x7fffu + ((c.u >> 16) & 1u);   // round-to-nearest-even
    return (unsigned short)(r >> 16);
}

union BF8 { bf16x8 v; unsigned short s[8]; };

// ---------------------------------------------------------------------------
// GEMM: H8(biased uint8, per-row scale) = quant(X @ W^T), slab-major layout:
//   H8[slab][node][32]  (slab = ch>>5), stored value = clamp(rint(h/s))+128.
// Core unchanged from round 9 (W in 64KB swizzled LDS, X direct to A-frags).
// ---------------------------------------------------------------------------
__global__ __launch_bounds__(512, 4) void gemm_xwt(const float* __restrict__ X,
                                                   const float* __restrict__ W,
                                                   unsigned char* __restrict__ H8,
                                                   float* __restrict__ scale) {
    __shared__ unsigned short Wsh[128 * 256];   // bf16 bits, [n][k], swizzled, 64KB

    const int tid  = threadIdx.x;
    const int lane = tid & 63;
    const int wid  = tid >> 6;                  // 0..7

#pragma unroll
    for (int p = 0; p < 16; ++p) {
        int idx = p * 512 + tid;                // 0..8191 float4 index
        int n   = idx >> 6;                     // 0..127
        int c4  = idx & 63;                     // float4 column
        float4 v = *(const float4*)(W + (size_t)n * IN_C + c4 * 4);
        int byte = (n * 512 + c4 * 8) ^ ((n & 7) << 4);
        *(ushort4*)((char*)Wsh + byte) =
            make_ushort4(f2bf(v.x), f2bf(v.y), f2bf(v.z), f2bf(v.w));
    }
    __syncthreads();

    const int r0   = blockIdx.x * 128 + wid * 16;
    int arow = r0 + (lane & 15);
    if (arow > NNODES - 1) arow = NNODES - 1;   // clamp (tail rows discarded)
    const float* xrow = X + (size_t)arow * IN_C + (lane >> 4) * 8;

    f32x4 acc[8] = {};
#pragma unroll
    for (int ks = 0; ks < 8; ++ks) {
        float4 a0 = *(const float4*)(xrow + ks * 32);
        float4 a1 = *(const float4*)(xrow + ks * 32 + 4);
        BF8 t;
        t.s[0] = f2bf(a0.x); t.s[1] = f2bf(a0.y); t.s[2] = f2bf(a0.z); t.s[3] = f2bf(a0.w);
        t.s[4] = f2bf(a1.x); t.s[5] = f2bf(a1.y); t.s[6] = f2bf(a1.z); t.s[7] = f2bf(a1.w);
        const int kb = ks * 64 + (lane >> 4) * 16;      // byte offset in W row
#pragma unroll
        for (int n8 = 0; n8 < 8; ++n8) {
            int nr   = n8 * 16 + (lane & 15);
            int byte = (nr * 512 + kb) ^ ((nr & 7) << 4);
            bf16x8 b = *(const bf16x8*)((const char*)Wsh + byte);
            acc[n8] = __builtin_amdgcn_mfma_f32_16x16x32_bf16(t.v, b, acc[n8],
                                                              0, 0, 0);
        }
    }

    // --- epilogue: per-row amax -> biased-uint8 quantize, slab-major ---
    float amax[4];
#pragma unroll
    for (int r = 0; r < 4; ++r) {
        float m = 0.f;
#pragma unroll
        for (int n8 = 0; n8 < 8; ++n8) m = fmaxf(m, fabsf(acc[n8][r]));
        amax[r] = m;
    }
#pragma unroll
    for (int d = 1; d < 16; d <<= 1)
#pragma unroll
        for (int r = 0; r < 4; ++r)
            amax[r] = fmaxf(amax[r], __shfl_xor(amax[r], d));

#pragma unroll
    for (int r = 0; r < 4; ++r) {
        int grow = r0 + (lane >> 4) * 4 + r;
        if (grow < NNODES) {
            float am  = amax[r];
            float inv = am > 0.f ? 127.f / am : 0.f;
            if ((lane & 15) == 0) scale[grow] = am * (1.f / 127.f);
#pragma unroll
            for (int n8 = 0; n8 < 8; ++n8) {
                float q = rintf(acc[n8][r] * inv);
                q = fminf(127.f, fmaxf(-127.f, q));
                // ch = n8*16 + (lane&15); slab = n8>>1
                size_t off = (size_t)(n8 >> 1) * (NNODES * 32)
                           + (size_t)grow * 32 + (n8 & 1) * 16 + (lane & 15);
                H8[off] = (unsigned char)((int)q + 128);
            }
        }
    }
}

// ---------------------------------------------------------------------------
// rowptr[r] = lower_bound(A_rows, r)  (A_rows sorted).  r in [0, N].
// ---------------------------------------------------------------------------
__global__ __launch_bounds__(256) void build_rowptr(const int* __restrict__ rows,
                                                    int* __restrict__ rowptr) {
    int r = blockIdx.x * 256 + threadIdx.x;
    if (r > NNODES) return;
    int lo = 0, hi = NEDGES;
    while (lo < hi) {
        int mid = (lo + hi) >> 1;
        if (rows[mid] < r) lo = mid + 1; else hi = mid;
    }
    rowptr[r] = lo;
}

// ---------------------------------------------------------------------------
// SpMM, slab-partitioned: block b -> XCD (b&7); slab = (b&7)>>1 (32 channels).
// Each XCD's H slab = 3.2 MB -> resident in its private 4MB L2 -> gathers hit.
// ONE ROW PER LANE: no shfl, no cross-lane reduce; lane walks its row's edges,
// gathers 2x uint4 (32 biased-uint8 ch), unpacks via v_cvt_f32_ubyteN, and
// writes one full 128B out line. Bias correction -128*sum(w) applied at end.
// ---------------------------------------------------------------------------
__global__ __launch_bounds__(256) void spmm_rows(const unsigned char* __restrict__ H8,
                                                 const int* __restrict__ rowptr,
                                                 const int* __restrict__ cols,
                                                 const float* __restrict__ vals,
                                                 const float* __restrict__ scale,
                                                 float* __restrict__ out) {
    const int b     = blockIdx.x;
    const int slab  = (b & 7) >> 1;                 // 0..3
    const int chunk = (b >> 3) * 2 + (b & 1);       // 0..391
    const int row   = chunk * 256 + threadIdx.x;
    if (row >= NNODES) return;

    const unsigned char* Hs = H8 + (size_t)slab * (NNODES * 32);

    const int s = rowptr[row];
    const int e = rowptr[row + 1];

    float acc[32];
#pragma unroll
    for (int t = 0; t < 32; ++t) acc[t] = 0.f;
    float sw = 0.f;

#pragma unroll 2
    for (int i = s; i < e; ++i) {
        int   c = cols[i];
        float w = vals[i] * scale[c];
        const uint4* hp = (const uint4*)(Hs + (size_t)c * 32);
        uint4 u0 = hp[0];
        uint4 u1 = hp[1];
        sw += w;
#pragma unroll
        for (int d = 0; d < 4; ++d) {
            unsigned ud = (&u0.x)[d];
            acc[d * 4 + 0] += w * (float)( ud        & 0xffu);
            acc[d * 4 + 1] += w * (float)((ud >>  8) & 0xffu);
            acc[d * 4 + 2] += w * (float)((ud >> 16) & 0xffu);
            acc[d * 4 + 3] += w * (float)( ud >> 24);
        }
#pragma unroll
        for (int d = 0; d < 4; ++d) {
            unsigned ud = (&u1.x)[d];
            acc[16 + d * 4 + 0] += w * (float)( ud        & 0xffu);
            acc[16 + d * 4 + 1] += w * (float)((ud >>  8) & 0xffu);
            acc[16 + d * 4 + 2] += w * (float)((ud >> 16) & 0xffu);
            acc[16 + d * 4 + 3] += w * (float)( ud >> 24);
        }
    }

    // bias correction and store: one full 128B line per lane
    float* orow = out + (size_t)row * OUT_C + slab * 32;
#pragma unroll
    for (int t = 0; t < 8; ++t) {
        f32x4 v = { acc[t * 4 + 0] - 128.f * sw,
                    acc[t * 4 + 1] - 128.f * sw,
                    acc[t * 4 + 2] - 128.f * sw,
                    acc[t * 4 + 3] - 128.f * sw };
        __builtin_nontemporal_store(v, (f32x4*)(orow + t * 4));
    }
}

// ---------------------------------------------------------------------------
extern "C" void kernel_launch(void* const* d_in, const int* in_sizes, int n_in,
                              void* d_out, int out_size, void* d_ws, size_t ws_size,
                              hipStream_t stream) {
    const float* X      = (const float*)d_in[0];
    const float* W      = (const float*)d_in[1];
    const int*   A_rows = (const int*)d_in[2];
    const int*   A_cols = (const int*)d_in[3];
    const float* A_vals = (const float*)d_in[4];
    float* out = (float*)d_out;

    unsigned char* H8    = (unsigned char*)d_ws;                        // 12.8 MB
    float*         scale = (float*)((char*)d_ws + (size_t)NNODES * OUT_C); // 400 KB
    int*           rowptr = (int*)((char*)scale + (size_t)NNODES * sizeof(float));

    gemm_xwt<<<(NNODES + 127) / 128, 512, 0, stream>>>(X, W, H8, scale);
    build_rowptr<<<(NNODES + 1 + 255) / 256, 256, 0, stream>>>(A_rows, rowptr);
    // 392 chunks of 256 rows, x2 XCD-lanes per slab, x4 slabs = 1568 blocks
    spmm_rows<<<8 * 196, 256, 0, stream>>>(H8, rowptr, A_cols, A_vals, scale, out);
}

// Round 12
// 94.855 us; speedup vs baseline: 2.1341x; 2.1341x over previous
//
#include <hip/hip_runtime.h>
#include <hip/hip_bf16.h>

#define NNODES 100000
#define NEDGES 1600000
#define IN_C   256
#define OUT_C  128

typedef short bf16x8 __attribute__((ext_vector_type(8)));
typedef float f32x4  __attribute__((ext_vector_type(4)));

static __device__ __forceinline__ unsigned short f2bf(float f) {
    union { float f; unsigned u; } c; c.f = f;
    unsigned r = c.u + 0x7fffu + ((c.u >> 16) & 1u);   // round-to-nearest-even
    return (unsigned short)(r >> 16);
}

union BF8 { bf16x8 v; unsigned short s[8]; };

// ---------------------------------------------------------------------------
// GEMM: H8(biased uint8, row-major, per-row scale) = quant(X @ W^T).
// Core = round-9/10 verified structure (W in 64KB swizzled LDS, X direct to
// A-frags, barrier-free K-loop). Epilogue stores q+128 as uint8.
// ---------------------------------------------------------------------------
__global__ __launch_bounds__(512, 4) void gemm_xwt(const float* __restrict__ X,
                                                   const float* __restrict__ W,
                                                   unsigned char* __restrict__ H8,
                                                   float* __restrict__ scale) {
    __shared__ unsigned short Wsh[128 * 256];   // bf16 bits, [n][k], swizzled, 64KB

    const int tid  = threadIdx.x;
    const int lane = tid & 63;
    const int wid  = tid >> 6;                  // 0..7

#pragma unroll
    for (int p = 0; p < 16; ++p) {
        int idx = p * 512 + tid;                // 0..8191 float4 index
        int n   = idx >> 6;                     // 0..127
        int c4  = idx & 63;                     // float4 column
        float4 v = *(const float4*)(W + (size_t)n * IN_C + c4 * 4);
        int byte = (n * 512 + c4 * 8) ^ ((n & 7) << 4);
        *(ushort4*)((char*)Wsh + byte) =
            make_ushort4(f2bf(v.x), f2bf(v.y), f2bf(v.z), f2bf(v.w));
    }
    __syncthreads();

    const int r0   = blockIdx.x * 128 + wid * 16;
    int arow = r0 + (lane & 15);
    if (arow > NNODES - 1) arow = NNODES - 1;   // clamp (tail rows discarded)
    const float* xrow = X + (size_t)arow * IN_C + (lane >> 4) * 8;

    f32x4 acc[8] = {};
#pragma unroll
    for (int ks = 0; ks < 8; ++ks) {
        float4 a0 = *(const float4*)(xrow + ks * 32);
        float4 a1 = *(const float4*)(xrow + ks * 32 + 4);
        BF8 t;
        t.s[0] = f2bf(a0.x); t.s[1] = f2bf(a0.y); t.s[2] = f2bf(a0.z); t.s[3] = f2bf(a0.w);
        t.s[4] = f2bf(a1.x); t.s[5] = f2bf(a1.y); t.s[6] = f2bf(a1.z); t.s[7] = f2bf(a1.w);
        const int kb = ks * 64 + (lane >> 4) * 16;      // byte offset in W row
#pragma unroll
        for (int n8 = 0; n8 < 8; ++n8) {
            int nr   = n8 * 16 + (lane & 15);
            int byte = (nr * 512 + kb) ^ ((nr & 7) << 4);
            bf16x8 b = *(const bf16x8*)((const char*)Wsh + byte);
            acc[n8] = __builtin_amdgcn_mfma_f32_16x16x32_bf16(t.v, b, acc[n8],
                                                              0, 0, 0);
        }
    }

    // --- epilogue: per-row amax -> biased-uint8 quantize (row-major) ---
    float amax[4];
#pragma unroll
    for (int r = 0; r < 4; ++r) {
        float m = 0.f;
#pragma unroll
        for (int n8 = 0; n8 < 8; ++n8) m = fmaxf(m, fabsf(acc[n8][r]));
        amax[r] = m;
    }
#pragma unroll
    for (int d = 1; d < 16; d <<= 1)
#pragma unroll
        for (int r = 0; r < 4; ++r)
            amax[r] = fmaxf(amax[r], __shfl_xor(amax[r], d));

#pragma unroll
    for (int r = 0; r < 4; ++r) {
        int grow = r0 + (lane >> 4) * 4 + r;
        if (grow < NNODES) {
            float am  = amax[r];
            float inv = am > 0.f ? 127.f / am : 0.f;
            if ((lane & 15) == 0) scale[grow] = am * (1.f / 127.f);
#pragma unroll
            for (int n8 = 0; n8 < 8; ++n8) {
                float q = rintf(acc[n8][r] * inv);
                q = fminf(127.f, fmaxf(-127.f, q));
                H8[(size_t)grow * OUT_C + n8 * 16 + (lane & 15)] =
                    (unsigned char)((int)q + 128);
            }
        }
    }
}

// ---------------------------------------------------------------------------
// rowptr[r] = lower_bound(A_rows, r)  (A_rows sorted).  r in [0, N].
// ---------------------------------------------------------------------------
__global__ __launch_bounds__(256) void build_rowptr(const int* __restrict__ rows,
                                                    int* __restrict__ rowptr) {
    int r = blockIdx.x * 256 + threadIdx.x;
    if (r > NNODES) return;
    int lo = 0, hi = NEDGES;
    while (lo < hi) {
        int mid = (lo + hi) >> 1;
        if (rows[mid] < r) lo = mid + 1; else hi = mid;
    }
    rowptr[r] = lo;
}

// ---------------------------------------------------------------------------
// SpMM: out[r,:] = sum_e vals[e]*scale[c_e] * H8[c_e,:].
// Round-10 two-row pipeline + ISSUE/CONSUME SPLIT: per 16-edge step, all 8
// gather addresses are shfl'd and all 8 uint2 gathers issued back-to-back
// (wave-uniform guards), then the 8 FMA blocks consume in issue order ->
// 4-8 loads in flight per wave instead of 1-2.
// Biased-uint8 unpack: v_cvt_f32_ubyteN + fma (2 inst/ch); exact correction
// -128*sum(w) applied after the cross-group reduce.
// ---------------------------------------------------------------------------
static __device__ __forceinline__ void fma8(float acc[8], float* sw,
                                            uint2 u, float v) {
    *sw += v;
    acc[0] += v * (float)( u.x        & 0xffu);
    acc[1] += v * (float)((u.x >>  8) & 0xffu);
    acc[2] += v * (float)((u.x >> 16) & 0xffu);
    acc[3] += v * (float)( u.x >> 24);
    acc[4] += v * (float)( u.y        & 0xffu);
    acc[5] += v * (float)((u.y >>  8) & 0xffu);
    acc[6] += v * (float)((u.y >> 16) & 0xffu);
    acc[7] += v * (float)( u.y >> 24);
}

__global__ __launch_bounds__(256) void spmm_rows(const uint2* __restrict__ H2,
                                                 const int* __restrict__ rowptr,
                                                 const int* __restrict__ cols,
                                                 const float* __restrict__ vals,
                                                 const float* __restrict__ scale,
                                                 float* __restrict__ out) {
    const int wid  = threadIdx.x >> 6;
    const int lane = threadIdx.x & 63;
    const int g    = lane >> 4;      // edge subgroup 0..3
    const int cg   = lane & 15;      // channel group: channels cg*8 .. cg*8+7

    const int rowA = (blockIdx.x * 4 + wid) * 2;   // rowB = rowA + 1
    const int sA = rowptr[rowA];
    const int eA = rowptr[rowA + 1];
    const int eB = rowptr[rowA + 2];

    float accA[8], accB[8];
#pragma unroll
    for (int t = 0; t < 8; ++t) { accA[t] = 0.f; accB[t] = 0.f; }
    float swA = 0.f, swB = 0.f;

    int baseA = sA, baseB = eA;
    while (baseA < eA || baseB < eB) {
        int cntA = eA - baseA; cntA = cntA < 0 ? 0 : (cntA > 64 ? 64 : cntA);
        int cntB = eB - baseB; cntB = cntB < 0 ? 0 : (cntB > 64 ? 64 : cntB);

        int   ecA = 0, ecB = 0;
        float evA = 0.f, evB = 0.f;
        if (lane < cntA) { ecA = cols[baseA + lane]; evA = vals[baseA + lane] * scale[ecA]; }
        if (lane < cntB) { ecB = cols[baseB + lane]; evB = vals[baseB + lane] * scale[ecB]; }

        const int mx = cntA > cntB ? cntA : cntB;
        for (int j = 0; j < mx; j += 16) {
            // wave-uniform guards (cnt identical across lanes)
            const bool dA0 = j      < cntA, dA1 = j +  4 < cntA,
                       dA2 = j + 8  < cntA, dA3 = j + 12 < cntA;
            const bool dB0 = j      < cntB, dB1 = j +  4 < cntB,
                       dB2 = j + 8  < cntB, dB3 = j + 12 < cntB;

            // ---- ISSUE phase: addresses then gathers, back-to-back ----
            int cA0 = __shfl(ecA, j + g),      cB0 = __shfl(ecB, j + g);
            int cA1 = __shfl(ecA, j + 4 + g),  cB1 = __shfl(ecB, j + 4 + g);
            int cA2 = __shfl(ecA, j + 8 + g),  cB2 = __shfl(ecB, j + 8 + g);
            int cA3 = __shfl(ecA, j + 12 + g), cB3 = __shfl(ecB, j + 12 + g);
            uint2 uA0, uA1, uA2, uA3, uB0, uB1, uB2, uB3;
            if (dA0) uA0 = H2[(size_t)cA0 * 16 + cg];
            if (dB0) uB0 = H2[(size_t)cB0 * 16 + cg];
            if (dA1) uA1 = H2[(size_t)cA1 * 16 + cg];
            if (dB1) uB1 = H2[(size_t)cB1 * 16 + cg];
            if (dA2) uA2 = H2[(size_t)cA2 * 16 + cg];
            if (dB2) uB2 = H2[(size_t)cB2 * 16 + cg];
            if (dA3) uA3 = H2[(size_t)cA3 * 16 + cg];
            if (dB3) uB3 = H2[(size_t)cB3 * 16 + cg];

            // ---- CONSUME phase: FMAs in issue order ----
            if (dA0) fma8(accA, &swA, uA0, __shfl(evA, j + g));
            if (dB0) fma8(accB, &swB, uB0, __shfl(evB, j + g));
            if (dA1) fma8(accA, &swA, uA1, __shfl(evA, j + 4 + g));
            if (dB1) fma8(accB, &swB, uB1, __shfl(evB, j + 4 + g));
            if (dA2) fma8(accA, &swA, uA2, __shfl(evA, j + 8 + g));
            if (dB2) fma8(accB, &swB, uB2, __shfl(evB, j + 8 + g));
            if (dA3) fma8(accA, &swA, uA3, __shfl(evA, j + 12 + g));
            if (dB3) fma8(accB, &swB, uB3, __shfl(evB, j + 12 + g));
        }

        baseA += cntA;
        baseB += cntB;
    }

    // reduce across the 4 edge subgroups, then exact bias correction
#pragma unroll
    for (int t = 0; t < 8; ++t) {
        accA[t] += __shfl_xor(accA[t], 16);
        accA[t] += __shfl_xor(accA[t], 32);
        accB[t] += __shfl_xor(accB[t], 16);
        accB[t] += __shfl_xor(accB[t], 32);
    }
    swA += __shfl_xor(swA, 16); swA += __shfl_xor(swA, 32);
    swB += __shfl_xor(swB, 16); swB += __shfl_xor(swB, 32);

    if (lane < 16) {
        const float bA = 128.f * swA, bB = 128.f * swB;
        f32x4 a0 = { accA[0] - bA, accA[1] - bA, accA[2] - bA, accA[3] - bA };
        f32x4 a1 = { accA[4] - bA, accA[5] - bA, accA[6] - bA, accA[7] - bA };
        f32x4 b0 = { accB[0] - bB, accB[1] - bB, accB[2] - bB, accB[3] - bB };
        f32x4 b1 = { accB[4] - bB, accB[5] - bB, accB[6] - bB, accB[7] - bB };
        __builtin_nontemporal_store(a0, (f32x4*)(out + (size_t)rowA * OUT_C + cg * 8));
        __builtin_nontemporal_store(a1, (f32x4*)(out + (size_t)rowA * OUT_C + cg * 8 + 4));
        __builtin_nontemporal_store(b0, (f32x4*)(out + (size_t)(rowA + 1) * OUT_C + cg * 8));
        __builtin_nontemporal_store(b1, (f32x4*)(out + (size_t)(rowA + 1) * OUT_C + cg * 8 + 4));
    }
}

// ---------------------------------------------------------------------------
extern "C" void kernel_launch(void* const* d_in, const int* in_sizes, int n_in,
                              void* d_out, int out_size, void* d_ws, size_t ws_size,
                              hipStream_t stream) {
    const float* X      = (const float*)d_in[0];
    const float* W      = (const float*)d_in[1];
    const int*   A_rows = (const int*)d_in[2];
    const int*   A_cols = (const int*)d_in[3];
    const float* A_vals = (const float*)d_in[4];
    float* out = (float*)d_out;

    unsigned char* H8    = (unsigned char*)d_ws;                        // 12.8 MB
    float*         scale = (float*)((char*)d_ws + (size_t)NNODES * OUT_C); // 400 KB
    int*           rowptr = (int*)((char*)scale + (size_t)NNODES * sizeof(float));

    gemm_xwt<<<(NNODES + 127) / 128, 512, 0, stream>>>(X, W, H8, scale);
    build_rowptr<<<(NNODES + 1 + 255) / 256, 256, 0, stream>>>(A_rows, rowptr);
    spmm_rows<<<(NNODES + 7) / 8, 256, 0, stream>>>((const uint2*)H8, rowptr,
                                                    A_cols, A_vals, scale, out);
}